// Round 9
// baseline (108.959 us; speedup 1.0000x reference)
//
#include <hip/hip_runtime.h>
#include <hip/hip_bf16.h>
#include <stdint.h>

#define NBATCH 16
#define SEQ 4096
#define DIM 256
#define MEM 40
#define KTOT 512            // interleaved K: k=2d -> x*W1, k=2d+1 -> h*W2
#define MTOT (NBATCH*SEQ)   // 65536 rows

typedef unsigned short u16;
typedef __attribute__((ext_vector_type(8))) short short8;
typedef __attribute__((ext_vector_type(4))) float f32x4;

typedef __attribute__((address_space(1))) const void gvoid_t;
typedef __attribute__((address_space(3))) void lvoid_t;

static __device__ __forceinline__ u16 f2bf(float f) {
    union { float f; uint32_t u; } v; v.f = f;
    uint32_t u = v.u;
    u += 0x7FFFu + ((u >> 16) & 1);   // RTNE (finite values only)
    return (u16)(u >> 16);
}

// ---------------------------------------------------------------------------
// Build B^T (bf16) with interleaved K: BmT32[n*256 + d] = pack(W1[d][n], W2[d][n])
// ---------------------------------------------------------------------------
__global__ __launch_bounds__(256) void k_bmat(const float* __restrict__ W1,
                                              const float* __restrict__ W2,
                                              uint32_t* __restrict__ BmT32) {
    const int n = blockIdx.x;
    const int d = threadIdx.x;
    float w1 = W1[d * DIM + n];
    float w2 = W2[d * DIM + n];
    BmT32[n * DIM + d] = (uint32_t)f2bf(w1) | ((uint32_t)f2bf(w2) << 16);
}

// ---------------------------------------------------------------------------
// FIR conv v8: float2 (2 channels/thread) + 4-way tap split.
// R7 diagnosis: structure clean (FETCH=1 pass, no spill) but 4B/lane scalar
// loads+stores cap BW at 2 TB/s (G13). v8: lane = c2 + 16g; thread owns
// channels {2c2, 2c2+1}; group g owns taps 10g+1..10g+10 (its own load
// stream time-shifted by 10g -- independent streams, NO handoff chain,
// L2 absorbs the 4x overlap as proven in R6/R7). 8B/lane loads, uint2 8B
// stores. Reduction = 2 butterfly shfl_xor stages. State: wt2[10]+hist2[10]
// +cur2[4]+h2[4] ~ 72 regs, all static, slide-by-4 renames.
// ---------------------------------------------------------------------------
#define TW 64    // timesteps per wave

template <bool GUARD>
__device__ __forceinline__ void conv_wave(const float2* __restrict__ xb,   // +dpair
                                          uint2* __restrict__ Ab,          // +dpair
                                          const float2* __restrict__ mwp,  // +dpair
                                          float* __restrict__ total,
                                          int dpair, int b, int t0, int g, bool lead) {
    const int LD = DIM / 2;
    const float2 mw0 = mwp[0];
    float2 wt[10];
#pragma unroll
    for (int j = 0; j < 10; ++j) {                 // taps 10g+1 .. 10g+10
        float2 m = mwp[(size_t)(10 * g + 1 + j) * LD];
        wt[j] = make_float2(m.x - mw0.x, m.y - mw0.y);
    }

    const int tg = t0 - 10 * g;                    // group-local time origin
    float2 hist[10];                               // hist[m] = x2[tg-10+m]
#pragma unroll
    for (int m = 0; m < 10; ++m) {
        int t = tg - 10 + m;
        if (GUARD) hist[m] = (t >= 0) ? xb[(size_t)t * LD] : make_float2(0.f, 0.f);
        else       hist[m] = xb[(size_t)t * LD];
    }

    float2 colsum = make_float2(0.f, 0.f);
#pragma unroll
    for (int ch = 0; ch < TW / 4; ++ch) {          // 16 chunks of 4 outputs
        float2 cur[4];
#pragma unroll
        for (int i = 0; i < 4; ++i) {
            int tt = tg + ch * 4 + i;
            if (GUARD) cur[i] = (tt >= 0) ? xb[(size_t)tt * LD] : make_float2(0.f, 0.f);
            else       cur[i] = xb[(size_t)tt * LD];
        }
        // output i uses C[i..i+9], C[m] = (m<10) ? hist[m] : cur[m-10]
        float2 h[4];
#pragma unroll
        for (int i = 0; i < 4; ++i) {
            float ax0 = 0.f, ay0 = 0.f, ax1 = 0.f, ay1 = 0.f;   // 2x ILP
#pragma unroll
            for (int j = 0; j < 10; ++j) {         // tap 10g+1+j uses C[i+9-j]
                int m = i + 9 - j;
                float2 v = (m < 10) ? hist[m] : cur[m - 10];
                if (j & 1) { ax1 = fmaf(wt[j].x, v.x, ax1); ay1 = fmaf(wt[j].y, v.y, ay1); }
                else       { ax0 = fmaf(wt[j].x, v.x, ax0); ay0 = fmaf(wt[j].y, v.y, ay0); }
            }
            h[i] = make_float2(ax0 + ax1, ay0 + ay1);
        }
#pragma unroll
        for (int i = 0; i < 4; ++i) {
            float hx = h[i].x;
            hx += __shfl_xor(hx, 16, 64);
            hx += __shfl_xor(hx, 32, 64);
            float hy = h[i].y;
            hy += __shfl_xor(hy, 16, 64);
            hy += __shfl_xor(hy, 32, 64);
            if (lead) {
                colsum.x += cur[i].x;
                colsum.y += cur[i].y;
                __hip_bfloat162 p0 = __float22bfloat162_rn(make_float2(cur[i].x, hx));
                __hip_bfloat162 p1 = __float22bfloat162_rn(make_float2(cur[i].y, hy));
                uint2 st;
                st.x = *reinterpret_cast<uint32_t*>(&p0);
                st.y = *reinterpret_cast<uint32_t*>(&p1);
                Ab[(size_t)(t0 + ch * 4 + i) * LD] = st;
            }
        }
        // slide by 4
#pragma unroll
        for (int m = 0; m < 6; ++m) hist[m] = hist[m + 4];
#pragma unroll
        for (int m = 6; m < 10; ++m) hist[m] = cur[m - 6];
    }
    if (lead) {
        atomicAdd(&total[b * DIM + dpair], colsum.x);
        atomicAdd(&total[b * DIM + dpair + 1], colsum.y);
    }
}

__global__ void k_conv(const float* __restrict__ x,
                       const float* __restrict__ mw,
                       uint32_t* __restrict__ Aout,
                       float* __restrict__ total) {
    const int tid  = threadIdx.x;
    const int lane = tid & 63;
    const int w    = tid >> 6;           // 4 waves
    const int c2   = lane & 15;          // float2 pair index (16 pairs = 32 ch)
    const int g    = lane >> 4;          // tap quarter 0..3
    const int b    = blockIdx.y;
    const int t0   = blockIdx.x * TW;
    const int dpair = blockIdx.z * 128 + w * 32 + c2 * 2;

    const float2* xb  = (const float2*)(x + (size_t)b * SEQ * DIM + dpair);
    uint2* Ab         = (uint2*)(Aout + (size_t)b * SEQ * DIM + dpair);
    const float2* mwp = (const float2*)(mw + dpair);

    if (blockIdx.x == 0)
        conv_wave<true >(xb, Ab, mwp, total, dpair, b, t0, g, g == 0);
    else
        conv_wave<false>(xb, Ab, mwp, total, dpair, b, t0, g, g == 0);
}

// ---------------------------------------------------------------------------
// corr[b][n] = bias[n] + sum_d mw[0][d] * total[b][d] * W2[d][n]
// ---------------------------------------------------------------------------
__global__ __launch_bounds__(256) void k_corr(const float* __restrict__ W2,
                                              const float* __restrict__ bias,
                                              const float* __restrict__ mw,
                                              const float* __restrict__ total,
                                              float* __restrict__ corr) {
    const int b = blockIdx.x;
    const int n = threadIdx.x;
    float s = bias[n];
    for (int dd = 0; dd < DIM; ++dd)
        s += mw[dd] * total[b * DIM + dd] * W2[dd * DIM + n];
    corr[b * DIM + n] = s;
}

// ---------------------------------------------------------------------------
// GEMM: out[M=65536, N=256] = A[M, 512](bf16) @ Bmat[512, 256](bf16) + corr[b]
// BM=128, BN=256, BK=64, 8 waves, 16x16x32 MFMA. XCD-aware bijective swizzle
// (512 blocks, 512%8==0) for L2 locality on the memory-bound A stream.
// ---------------------------------------------------------------------------
#define BM 128
#define BN 256
#define BK 64

__global__ __launch_bounds__(512) void k_gemm(const u16* A,
                                              const u16* __restrict__ BmT,
                                              const float* __restrict__ corr,
                                              float* out) {
    __shared__ __align__(16) u16 Alds[BM * BK];   // 16 KB, [row][k]
    __shared__ __align__(16) u16 Blds[BN * BK];   // 32 KB, [col][k]

    const int tid  = threadIdx.x;
    const int lane = tid & 63;
    const int w    = tid >> 6;     // 0..7
    const int wr   = w >> 2;       // 0..1  (M split)
    const int wc   = w & 3;        // 0..3  (N split)
    // XCD swizzle: 512 blocks -> 64 contiguous tiles per XCD
    const int bid  = blockIdx.x;
    const int swz  = (bid & 7) * 64 + (bid >> 3);
    const int m0   = swz * BM;

    f32x4 acc[4][4] = {};

    for (int kt = 0; kt < KTOT / BK; ++kt) {
        const int k0 = kt * BK;
        // ---- stage A tile [128][64] : 1024 x 16B chunks, 2 per thread
#pragma unroll
        for (int i = 0; i < 2; ++i) {
            int c   = i * 512 + tid;
            int row = c >> 3;
            int kin = (c & 7) * 8;
            const u16* g = A + ((size_t)(m0 + row) * KTOT + k0 + kin);
            char* l = (char*)Alds + (size_t)(i * 512 + (tid & ~63)) * 16;
            __builtin_amdgcn_global_load_lds((gvoid_t*)g, (lvoid_t*)l, 16, 0, 0);
        }
        // ---- stage B tile [256 cols][64 k] from BmT[n][k] : 2048 chunks, 4/thread
#pragma unroll
        for (int i = 0; i < 4; ++i) {
            int c   = i * 512 + tid;
            int n   = c >> 3;
            int kin = (c & 7) * 8;
            const u16* g = BmT + ((size_t)n * KTOT + k0 + kin);
            char* l = (char*)Blds + (size_t)(i * 512 + (tid & ~63)) * 16;
            __builtin_amdgcn_global_load_lds((gvoid_t*)g, (lvoid_t*)l, 16, 0, 0);
        }
        __syncthreads();

#pragma unroll
        for (int kk = 0; kk < 2; ++kk) {
            short8 af[4], bfr[4];
#pragma unroll
            for (int mi = 0; mi < 4; ++mi) {
                int r = wr * 64 + mi * 16 + (lane & 15);
                af[mi] = *(const short8*)(Alds + r * BK + kk * 32 + ((lane >> 4) * 8));
            }
#pragma unroll
            for (int ni = 0; ni < 4; ++ni) {
                int ccol = wc * 64 + ni * 16 + (lane & 15);
                bfr[ni] = *(const short8*)(Blds + ccol * BK + kk * 32 + ((lane >> 4) * 8));
            }
#pragma unroll
            for (int mi = 0; mi < 4; ++mi)
#pragma unroll
                for (int ni = 0; ni < 4; ++ni)
                    acc[mi][ni] = __builtin_amdgcn_mfma_f32_16x16x32_bf16(
                        af[mi], bfr[ni], acc[mi][ni], 0, 0, 0);
        }
        __syncthreads();
    }

    // ---- epilogue: out = acc + corr[b][col]
    const int bidx = m0 >> 12;           // 4096 rows per batch, BM=128 divides it
    const float* corr_b = corr + bidx * DIM;
#pragma unroll
    for (int ni = 0; ni < 4; ++ni) {
        int col = wc * 64 + ni * 16 + (lane & 15);
        float cv = corr_b[col];
#pragma unroll
        for (int mi = 0; mi < 4; ++mi) {
            int rbase = m0 + wr * 64 + mi * 16 + ((lane >> 4) * 4);
#pragma unroll
            for (int j = 0; j < 4; ++j)
                out[(size_t)(rbase + j) * DIM + col] = acc[mi][ni][j] + cv;
        }
    }
}

// ---------------------------------------------------------------------------
extern "C" void kernel_launch(void* const* d_in, const int* in_sizes, int n_in,
                              void* d_out, int out_size, void* d_ws, size_t ws_size,
                              hipStream_t stream) {
    const float* x    = (const float*)d_in[0];
    const float* W1   = (const float*)d_in[1];
    const float* W2   = (const float*)d_in[2];
    const float* bias = (const float*)d_in[3];
    const float* mw   = (const float*)d_in[4];
    float* out = (float*)d_out;

    // ws layout: BmT (256*512*2 = 256KB) | total (16KB) | corr (16KB)
    u16*   BmT   = (u16*)d_ws;
    float* total = (float*)((char*)d_ws + 262144);
    float* corr  = (float*)((char*)d_ws + 262144 + 16384);

    hipMemsetAsync(total, 0, NBATCH * DIM * sizeof(float), stream);
    k_bmat<<<dim3(DIM), dim3(256), 0, stream>>>(W1, W2, (uint32_t*)BmT);
    k_conv<<<dim3(SEQ / TW, NBATCH, 2), dim3(256), 0, stream>>>(
        x, mw, (uint32_t*)d_out, total);
    k_corr<<<dim3(NBATCH), dim3(256), 0, stream>>>(W2, bias, mw, total, corr);
    k_gemm<<<dim3(MTOT / BM), dim3(512), 0, stream>>>(
        (const u16*)d_out, BmT, corr, out);
}